// Round 2
// baseline (551.864 us; speedup 1.0000x reference)
//
#include <hip/hip_runtime.h>
#include <hip/hip_bf16.h>

typedef unsigned short u16;
typedef __bf16 bf16x8 __attribute__((ext_vector_type(8)));
typedef unsigned short u16x8 __attribute__((ext_vector_type(8)));
typedef unsigned short u16x4 __attribute__((ext_vector_type(4)));
typedef float f32x2 __attribute__((ext_vector_type(2)));
typedef float f32x4 __attribute__((ext_vector_type(4)));
typedef float f32x16 __attribute__((ext_vector_type(16)));

#define B_ 8
#define T_ 2048
#define E_ 1024
#define H_ 1024
#define M_ (B_ * T_)   // 16384
#define INF __builtin_inff()

__device__ inline u16 f2bf(float f) {
    __bf16 h = (__bf16)f;
    return __builtin_bit_cast(u16, h);
}
__device__ inline float bf2f(u16 u) {
    unsigned v = (unsigned)u << 16;
    return __builtin_bit_cast(float, v);
}
__device__ inline bf16x8 load_frag(const u16* p) {
    u16x8 u = *(const u16x8*)p;
    return __builtin_bit_cast(bf16x8, u);
}
__device__ inline void gload_lds16(const u16* g, u16* l) {
    __builtin_amdgcn_global_load_lds(
        (__attribute__((address_space(1))) unsigned int*)(g),
        (__attribute__((address_space(3))) unsigned int*)(l), 16, 0, 0);
}

// ---------------- cast fp32 -> bf16 ----------------
__global__ void castk(const float* __restrict__ in, u16* __restrict__ out, int n) {
    int i = (blockIdx.x * blockDim.x + threadIdx.x) * 4;
    if (i < n) {
        f32x4 f = *(const f32x4*)(in + i);
        u16x4 u;
        u[0] = f2bf(f[0]); u[1] = f2bf(f[1]); u[2] = f2bf(f[2]); u[3] = f2bf(f[3]);
        *(u16x4*)(out + i) = u;
    }
}

// ---------------- fused QKV GEMM ----------------
__global__ __launch_bounds__(256) void gemm_qkv(const u16* __restrict__ A,
                                                const u16* __restrict__ W,
                                                u16* __restrict__ qo,
                                                u16* __restrict__ ko,
                                                u16* __restrict__ vo) {
    const int bm = blockIdx.x, bn = blockIdx.y;
    const int tid = threadIdx.x;
    const int w = tid >> 6, lane = tid & 63, quad = lane >> 4, l16 = lane & 15;
    const int wr = w & 1, wc = w >> 1;

    __shared__ u16 smem[128 * 128];
    u16* As = smem;
    u16* Bs = smem + 128 * 64;

    f32x4 acc[16] = {};

    const u16* Ab = A + (size_t)(bm * 128) * E_;
    const u16* Wb = W + (size_t)(bn * 128) * E_;

    for (int kk = 0; kk < E_; kk += 64) {
        __syncthreads();
#pragma unroll
        for (int i = 0; i < 4; i++) {
            int chunk = i * 256 + tid;
            int row = chunk >> 3, cc = chunk & 7;
            int ccs = cc ^ (row & 7);
            gload_lds16(Ab + (size_t)row * E_ + kk + ccs * 8, &As[chunk * 8]);
            gload_lds16(Wb + (size_t)row * E_ + kk + ccs * 8, &Bs[chunk * 8]);
        }
        __syncthreads();
#pragma unroll
        for (int k2 = 0; k2 < 2; k2++) {
            bf16x8 af[4], bf[4];
#pragma unroll
            for (int ri = 0; ri < 4; ri++) {
                int m = wr * 64 + ri * 16 + l16;
                int slot = m * 8 + ((k2 * 4 + quad) ^ (m & 7));
                af[ri] = load_frag(&As[slot * 8]);
            }
#pragma unroll
            for (int ci = 0; ci < 4; ci++) {
                int n = wc * 64 + ci * 16 + l16;
                int slot = n * 8 + ((k2 * 4 + quad) ^ (n & 7));
                bf[ci] = load_frag(&Bs[slot * 8]);
            }
#pragma unroll
            for (int ri = 0; ri < 4; ri++)
#pragma unroll
                for (int ci = 0; ci < 4; ci++)
                    acc[ri * 4 + ci] = __builtin_amdgcn_mfma_f32_16x16x32_bf16(
                        af[ri], bf[ci], acc[ri * 4 + ci], 0, 0, 0);
        }
    }

    // ---- epilogue: acc -> LDS bf16 (swizzled) -> coalesced stores ----
    __syncthreads();
    if (bn < 16) {
#pragma unroll
        for (int ri = 0; ri < 4; ri++)
#pragma unroll
            for (int ci = 0; ci < 4; ci++) {
                int n = wc * 64 + ci * 16 + l16;
#pragma unroll
                for (int r = 0; r < 4; r++) {
                    int m = wr * 64 + ri * 16 + quad * 4 + r;
                    smem[m * 128 + (((n >> 3) ^ (m & 15)) << 3) + (n & 7)] =
                        f2bf(acc[ri * 4 + ci][r]);
                }
            }
    } else {
#pragma unroll
        for (int ri = 0; ri < 4; ri++)
#pragma unroll
            for (int ci = 0; ci < 4; ci++) {
                int n = wc * 64 + ci * 16 + l16;
                int m0 = wr * 64 + ri * 16 + quad * 4;
                u16x4 pk;
#pragma unroll
                for (int r = 0; r < 4; r++) pk[r] = f2bf(acc[ri * 4 + ci][r]);
                *(u16x4*)&smem[n * 128 + (((m0 >> 3) ^ (n & 15)) << 3) + (m0 & 7)] = pk;
            }
    }
    __syncthreads();

    const int b = bm >> 4;
    if (bn < 8) {
#pragma unroll
        for (int i = 0; i < 8; i++) {
            int c = i * 256 + tid;
            int m = c >> 4, nc = c & 15;
            u16x8 v = *(u16x8*)&smem[m * 128 + ((nc ^ (m & 15)) << 3)];
            *(u16x8*)&qo[(size_t)(bm * 128 + m) * H_ + bn * 128 + nc * 8] = v;
        }
    } else if (bn < 16) {
#pragma unroll
        for (int i = 0; i < 8; i++) {
            int c = i * 256 + tid;
            int ln = c & 63, h16c = (c >> 6) & 7, s32c = c >> 9;
            int m = s32c * 32 + (ln & 31);
            int nc = h16c * 2 + (ln >> 5);
            u16x8 v = *(u16x8*)&smem[m * 128 + ((nc ^ (m & 15)) << 3)];
            int s32g = (bm & 15) * 4 + s32c;
            int h16g = (bn - 8) * 8 + h16c;
            *(u16x8*)&ko[(((size_t)b * 64 + s32g) * 64 + h16g) * 512 + ln * 8] = v;
        }
    } else {
#pragma unroll
        for (int i = 0; i < 8; i++) {
            int c = i * 256 + tid;
            int ln = c & 63, s16c = (c >> 6) & 7, h32c = c >> 9;
            int n = h32c * 32 + (ln & 31);
            int mc = s16c * 2 + (ln >> 5);
            u16x8 v = *(u16x8*)&smem[n * 128 + ((mc ^ (n & 15)) << 3)];
            int h32g = (bn - 16) * 4 + h32c;
            int s16g = (bm & 15) * 8 + s16c;
            *(u16x8*)&vo[(((size_t)b * 32 + h32g) * 128 + s16g) * 512 + ln * 8] = v;
        }
    }
}

// ---------------- flash attention v6: k-split load balance + K reg-prefetch ----------------
// Work units per batch (48): u<16: A-half of tile 16+u (s in [0,1024), 8 iters, partial);
// 16<=u<32: light tile 31-u (full, final write; cost 8..1 descending);
// u>=32: B-half of tile 63-u (s in [1024,t0], cost 8..1 descending, partial).
// All units cost <=8 iterations => LPT-ish dispatch gives makespan ~9-10 vs 16 before.
// batch = bid&7 keeps the batch->XCD L2 pinning.
__global__ __launch_bounds__(512, 2) void attn(const u16* __restrict__ qb,
                                               const u16* __restrict__ kfg,
                                               const u16* __restrict__ vfg,
                                               float* __restrict__ out,
                                               float* __restrict__ pout,
                                               f32x2* __restrict__ mlb) {
    const int bid = blockIdx.x;
    const int b = bid & 7;           // batch == XCD
    const int u = bid >> 3;          // 0..47, descending cost
    int tj, s_begin, mode;           // mode: 0 light-final, 1 A-partial, 2 B-partial
    if (u < 16)      { tj = 16 + u;  s_begin = 0;    mode = 1; }
    else if (u < 32) { tj = 31 - u;  s_begin = 0;    mode = 0; }
    else             { tj = 63 - u;  s_begin = 1024; mode = 2; }
    const int t0 = tj * 64;
    const int s_end = (mode == 1) ? 1024 : t0 + 64;

    const int tid = threadIdx.x;
    const int w = tid >> 6, lane = tid & 63;
    const int l5 = lane >> 5, l31 = lane & 31;
    const int srow = tid >> 3, sg = tid & 7;

    __shared__ u16 Qs[64 * 1024];    // 128 KB, [row][chunk ^ (row&7)]
    __shared__ u16 Sp[2 * 64 * 128]; // 32 KB: two bf16 [64][128] partials (chunk-swizzled)
    float* alphas = (float*)(Sp + 8192);  // aliases Sp1[0..255B]; written after Sp1 reads

    const u16* qB = qb + (size_t)b * T_ * H_;
    const u16* kfB = kfg + (size_t)b * 2097152;
    const u16* vfB = vfg + (size_t)b * 2097152;
    const float scale = 0.03125f;    // E^-0.5

    const int ct = w & 3;            // S col-tile (32 cols)
    const int kh = w >> 2;           // k-half

    // K reg-prefetch: first 8 frags of the upcoming iteration (loop-carried).
    bf16x8 kpre[8];
    {
        const u16* kp0 = kfB + (((size_t)((s_begin >> 5) + ct)) * 64 + kh * 32) * 512 + lane * 8;
#pragma unroll
        for (int i = 0; i < 8; i++) kpre[i] = load_frag(kp0 + i * 512);
    }

    // stage Q
#pragma unroll
    for (int i = 0; i < 16; i++) {
        int s = i * 512 + tid;
        int row = s >> 7, c = s & 127;
        int cc = c ^ (row & 7);
        gload_lds16(qB + (size_t)(t0 + row) * H_ + cc * 8, &Qs[s * 8]);
    }

    float m_r = -INF, l_r = 0.f;
    f32x16 o[2][4] = {};   // [rowgroup][h-tile]; wave w: H cols [w*128, w*128+128)

    __syncthreads();   // Q staged

    for (int s0 = s_begin; s0 < s_end; s0 += 128) {
        // ---- V prefetch group 0: hidden under the whole QK^T phase.
        const u16* vp = vfB + ((size_t)(w * 4) * 128 + (s0 >> 4)) * 512 + lane * 8;
        bf16x8 vbuf[3][4];
#pragma unroll
        for (int ht = 0; ht < 4; ht++)
            vbuf[0][ht] = load_frag(vp + (size_t)ht * 128 * 512);

        // ---- phase 1: partial scores, wave: cols ct*32..+32, k in [kh*512, kh*512+512)
        f32x16 sa0 = {}, sa1 = {};
        {
            const u16* kp = kfB + (((size_t)((s0 >> 5) + ct)) * 64 + kh * 32) * 512 + lane * 8;
            // st = 0..7 from register prefetch (issued last iteration / prologue)
#pragma unroll
            for (int st = 0; st < 8; st++) {
                bf16x8 kf = kpre[st];
                int cb = (kh * 32 + st) * 2 + l5;
                int x0 = l31 & 7;
                bf16x8 a0 = load_frag(&Qs[((size_t)l31 * 128 + (cb ^ x0)) * 8]);
                bf16x8 a1 = load_frag(&Qs[((size_t)(32 + l31) * 128 + (cb ^ x0)) * 8]);
                __builtin_amdgcn_s_setprio(1);
                sa0 = __builtin_amdgcn_mfma_f32_32x32x16_bf16(a0, kf, sa0, 0, 0, 0);
                sa1 = __builtin_amdgcn_mfma_f32_32x32x16_bf16(a1, kf, sa1, 0, 0, 0);
                __builtin_amdgcn_s_setprio(0);
            }
#pragma unroll 8
            for (int st = 8; st < 32; st++) {
                bf16x8 kf = load_frag(kp + st * 512);
                int cb = (kh * 32 + st) * 2 + l5;
                int x0 = l31 & 7;
                bf16x8 a0 = load_frag(&Qs[((size_t)l31 * 128 + (cb ^ x0)) * 8]);
                bf16x8 a1 = load_frag(&Qs[((size_t)(32 + l31) * 128 + (cb ^ x0)) * 8]);
                __builtin_amdgcn_s_setprio(1);
                sa0 = __builtin_amdgcn_mfma_f32_32x32x16_bf16(a0, kf, sa0, 0, 0, 0);
                sa1 = __builtin_amdgcn_mfma_f32_32x32x16_bf16(a1, kf, sa1, 0, 0, 0);
                __builtin_amdgcn_s_setprio(0);
            }
        }
        __syncthreads();   // prev PV done reading P(Sp0) + alphas(Sp1)
        {
            u16* Sdst = Sp + kh * 8192;
            int col = ct * 32 + l31;
            int chc = col >> 3, cil = col & 7;
#pragma unroll
            for (int reg = 0; reg < 16; reg++) {
                int row = (reg & 3) + 8 * (reg >> 2) + 4 * l5;
                Sdst[(row * 16 + (chc ^ (row & 7))) * 8 + cil] = f2bf(sa0[reg] * scale);
                int row1 = row + 32;
                Sdst[(row1 * 16 + (chc ^ (row1 & 7))) * 8 + cil] = f2bf(sa1[reg] * scale);
            }
        }
        __syncthreads();   // partials visible

        // ---- phase 2: softmax. thread (srow, sg): cols sg*16..+16
        {
            int sw0 = (sg * 2) ^ (srow & 7), sw1 = (sg * 2 + 1) ^ (srow & 7);
            u16x8 a0 = *(u16x8*)&Sp[(srow * 16 + sw0) * 8];
            u16x8 a1 = *(u16x8*)&Sp[(srow * 16 + sw1) * 8];
            u16x8 b0 = *(u16x8*)&Sp[8192 + (srow * 16 + sw0) * 8];
            u16x8 b1 = *(u16x8*)&Sp[8192 + (srow * 16 + sw1) * 8];
            float v[16];
#pragma unroll
            for (int j = 0; j < 8; j++) v[j] = bf2f(a0[j]) + bf2f(b0[j]);
#pragma unroll
            for (int j = 0; j < 8; j++) v[8 + j] = bf2f(a1[j]) + bf2f(b1[j]);
            int colb = sg * 16;
#pragma unroll
            for (int j = 0; j < 16; j++)
                if (s0 + colb + j > t0 + srow) v[j] = -INF;
            float rmax = v[0];
#pragma unroll
            for (int j = 1; j < 16; j++) rmax = fmaxf(rmax, v[j]);
#pragma unroll
            for (int off = 4; off >= 1; off >>= 1) rmax = fmaxf(rmax, __shfl_xor(rmax, off, 64));
            float mn = fmaxf(m_r, rmax);
            float alpha = __expf(m_r - mn);
            float rsum = 0.f;
            u16x8 p0, p1;
#pragma unroll
            for (int j = 0; j < 8; j++) {
                float p = __expf(v[j] - mn);
                rsum += p; p0[j] = f2bf(p);
            }
#pragma unroll
            for (int j = 0; j < 8; j++) {
                float p = __expf(v[8 + j] - mn);
                rsum += p; p1[j] = f2bf(p);
            }
#pragma unroll
            for (int off = 4; off >= 1; off >>= 1) rsum += __shfl_xor(rsum, off, 64);
            l_r = l_r * alpha + rsum;
            m_r = mn;
            *(u16x8*)&Sp[(srow * 16 + sw0) * 8] = p0;
            *(u16x8*)&Sp[(srow * 16 + sw1) * 8] = p1;
            __syncthreads();   // all Sp1 reads done
            if (sg == 0) alphas[srow] = alpha;
        }
        __syncthreads();   // P + alphas visible

        // ---- phase 3: PV + next-iteration K prefetch
        {
#pragma unroll
            for (int rg = 0; rg < 2; rg++)
#pragma unroll
                for (int reg = 0; reg < 16; reg++) {
                    float al = alphas[rg * 32 + (reg & 3) + 8 * (reg >> 2) + 4 * l5];
#pragma unroll
                    for (int ht = 0; ht < 4; ht++) o[rg][ht][reg] *= al;
                }
            // K prefetch for next iteration (lands during this PV + next QK^T head)
            if (s0 + 128 < s_end) {
                const u16* kpn = kfB + (((size_t)(((s0 + 128) >> 5) + ct)) * 64 + kh * 32) * 512 + lane * 8;
#pragma unroll
                for (int i = 0; i < 8; i++) kpre[i] = load_frag(kpn + i * 512);
            }
            int xp = l31 & 7;
#pragma unroll
            for (int ht = 0; ht < 4; ht++)
                vbuf[1][ht] = load_frag(vp + ((size_t)ht * 128 + 1) * 512);
#pragma unroll
            for (int sc = 0; sc < 8; sc++) {
                if (sc < 6) {
#pragma unroll
                    for (int ht = 0; ht < 4; ht++)
                        vbuf[(sc + 2) % 3][ht] = load_frag(vp + ((size_t)ht * 128 + sc + 2) * 512);
                }
                bf16x8 p0 = load_frag(&Sp[((size_t)l31 * 16 + ((sc * 2 + l5) ^ xp)) * 8]);
                bf16x8 p1 = load_frag(&Sp[((size_t)(32 + l31) * 16 + ((sc * 2 + l5) ^ xp)) * 8]);
                __builtin_amdgcn_s_setprio(1);
#pragma unroll
                for (int ht = 0; ht < 4; ht++) {
                    o[0][ht] = __builtin_amdgcn_mfma_f32_32x32x16_bf16(p0, vbuf[sc % 3][ht], o[0][ht], 0, 0, 0);
                    o[1][ht] = __builtin_amdgcn_mfma_f32_32x32x16_bf16(p1, vbuf[sc % 3][ht], o[1][ht], 0, 0, 0);
                }
                __builtin_amdgcn_s_setprio(0);
            }
        }
    }

    // ---- epilogue
    __syncthreads();
    if (sg == 0) alphas[srow] = l_r;
    __syncthreads();
    if (mode == 0) {
        float* ob = out + (size_t)b * T_ * H_;
#pragma unroll
        for (int rg = 0; rg < 2; rg++)
#pragma unroll
            for (int reg = 0; reg < 16; reg++) {
                int row = rg * 32 + (reg & 3) + 8 * (reg >> 2) + 4 * l5;
                float linv = 1.f / alphas[row];
#pragma unroll
                for (int ht = 0; ht < 4; ht++) {
                    int col = w * 128 + ht * 32 + l31;
                    ob[(size_t)(t0 + row) * H_ + col] = o[rg][ht][reg] * linv;
                }
            }
    } else {
        // partial write: unnormalized O + (m,l) per row
        if (sg == 0) {
            f32x2 t; t[0] = m_r; t[1] = l_r;
            mlb[((size_t)(b * 16 + (tj - 16)) * 2 + (mode - 1)) * 64 + srow] = t;
        }
        float* dst = (mode == 1) ? out + ((size_t)b * T_ + t0) * H_
                                 : pout + (size_t)((b * 16 + (tj - 16)) * 64) * 1024;
#pragma unroll
        for (int rg = 0; rg < 2; rg++)
#pragma unroll
            for (int reg = 0; reg < 16; reg++) {
                int row = rg * 32 + (reg & 3) + 8 * (reg >> 2) + 4 * l5;
#pragma unroll
                for (int ht = 0; ht < 4; ht++) {
                    int col = w * 128 + ht * 32 + l31;
                    dst[(size_t)row * 1024 + col] = o[rg][ht][reg];
                }
            }
    }
}

// ---------------- combine: merge A (in out) and B (in pout) halves ----------------
__global__ __launch_bounds__(256) void combine(const float* __restrict__ P,
                                               const f32x2* __restrict__ mlb,
                                               float* __restrict__ out) {
    const int bid = blockIdx.x;               // 256
    const int b = bid & 7, jt = (bid >> 3) & 15, rh = bid >> 7;
    const int t0 = (16 + jt) * 64;
    const int tcol = threadIdx.x;             // col = tcol*4
    const float* Pb = P + (size_t)((b * 16 + jt) * 64) * 1024;
    float* ob = out + ((size_t)b * T_ + t0) * H_;
    const f32x2* mlA = mlb + (size_t)(b * 16 + jt) * 2 * 64;
    const f32x2* mlB = mlA + 64;
#pragma unroll 4
    for (int r = rh * 32; r < rh * 32 + 32; r++) {
        f32x2 a = mlA[r], bb = mlB[r];
        float m = fmaxf(a[0], bb[0]);
        float wA = __expf(a[0] - m), wB = __expf(bb[0] - m);
        float denom = a[1] * wA + bb[1] * wB;
        float cA = wA / denom, cB = wB / denom;
        f32x4 oa = *(const f32x4*)&ob[(size_t)r * H_ + tcol * 4];
        f32x4 pv = *(const f32x4*)&Pb[(size_t)r * 1024 + tcol * 4];
        f32x4 res = oa * cA + pv * cB;
        *(f32x4*)&ob[(size_t)r * H_ + tcol * 4] = res;
    }
}

extern "C" void kernel_launch(void* const* d_in, const int* in_sizes, int n_in,
                              void* d_out, int out_size, void* d_ws, size_t ws_size,
                              hipStream_t stream) {
    const float* x  = (const float*)d_in[0];
    const float* Wk = (const float*)d_in[1];
    const float* Wq = (const float*)d_in[2];
    const float* Wv = (const float*)d_in[3];
    float* out = (float*)d_out;

    char* ws = (char*)d_ws;
    const size_t SZ_XB  = (size_t)M_ * E_ * 2;
    const size_t SZ_W   = (size_t)3 * H_ * E_ * 2;
    const size_t SZ_QKV = (size_t)M_ * H_ * 2;
    u16* xb   = (u16*)(ws);
    u16* wqkv = (u16*)(ws + SZ_XB);
    u16* qb   = (u16*)(ws + SZ_XB + SZ_W);
    u16* kfb  = (u16*)(ws + SZ_XB + SZ_W + SZ_QKV);
    u16* vfb  = (u16*)(ws + SZ_XB + SZ_W + 2 * SZ_QKV);
    // dead-after-gemm regions reused by attn partials (stream-serialized):
    float* pout = (float*)ws;           // over xb: 16 tiles * 64 * 1024 f32 * 8 batches = 32 MB
    f32x2* mlb  = (f32x2*)(ws + SZ_XB); // over wqkv: 128 KB

    castk<<<M_ * E_ / 4 / 256, 256, 0, stream>>>(x, xb, M_ * E_);
    castk<<<H_ * E_ / 4 / 256, 256, 0, stream>>>(Wq, wqkv, H_ * E_);
    castk<<<H_ * E_ / 4 / 256, 256, 0, stream>>>(Wk, wqkv + (size_t)H_ * E_, H_ * E_);
    castk<<<H_ * E_ / 4 / 256, 256, 0, stream>>>(Wv, wqkv + (size_t)2 * H_ * E_, H_ * E_);

    gemm_qkv<<<dim3(M_ / 128, 3072 / 128), 256, 0, stream>>>(xb, wqkv, qb, kfb, vfb);

    attn<<<dim3(384), 512, 0, stream>>>(qb, kfb, vfb, out, pout, mlb);
    combine<<<dim3(256), 256, 0, stream>>>(pout, mlb, out);
}

// Round 5
// 455.696 us; speedup vs baseline: 1.2110x; 1.2110x over previous
//
#include <hip/hip_runtime.h>
#include <hip/hip_bf16.h>

typedef unsigned short u16;
typedef __bf16 bf16x8 __attribute__((ext_vector_type(8)));
typedef unsigned short u16x8 __attribute__((ext_vector_type(8)));
typedef unsigned short u16x4 __attribute__((ext_vector_type(4)));
typedef float f32x4 __attribute__((ext_vector_type(4)));
typedef float f32x16 __attribute__((ext_vector_type(16)));

#define B_ 8
#define T_ 2048
#define E_ 1024
#define H_ 1024
#define M_ (B_ * T_)   // 16384
#define INF __builtin_inff()

__device__ inline u16 f2bf(float f) {
    __bf16 h = (__bf16)f;
    return __builtin_bit_cast(u16, h);
}
__device__ inline float bf2f(u16 u) {
    unsigned v = (unsigned)u << 16;
    return __builtin_bit_cast(float, v);
}
__device__ inline bf16x8 load_frag(const u16* p) {
    u16x8 u = *(const u16x8*)p;
    return __builtin_bit_cast(bf16x8, u);
}
__device__ inline void gload_lds16(const u16* g, u16* l) {
    __builtin_amdgcn_global_load_lds(
        (__attribute__((address_space(1))) unsigned int*)(g),
        (__attribute__((address_space(3))) unsigned int*)(l), 16, 0, 0);
}

// ---------------- cast fp32 -> bf16 ----------------
__global__ void castk(const float* __restrict__ in, u16* __restrict__ out, int n) {
    int i = (blockIdx.x * blockDim.x + threadIdx.x) * 4;
    if (i < n) {
        f32x4 f = *(const f32x4*)(in + i);
        u16x4 u;
        u[0] = f2bf(f[0]); u[1] = f2bf(f[1]); u[2] = f2bf(f[2]); u[3] = f2bf(f[3]);
        *(u16x4*)(out + i) = u;
    }
}

// ---------------- fused QKV GEMM: 256x256 tile, 4-phase/K-tile pipelined ----------------
// A: [16384][1024] bf16, W: [3072][1024] bf16 ([Wq;Wk;Wv])
// qo: row-major [M][1024]
// ko: frag-native for 32x32x16 B (n=s,k=h): [b][s/32][h/16][lane][8]
// vo: frag-native for 32x32x16 B (n=h,k=s): [b][h/32][s/16][lane][8]
// Schedule (T3+T4): per K-tile, full drain (__syncthreads: vmcnt(0)+barrier) at
// TILE START, before any ds_read of that buffer — drained loads were issued a
// full K-tile earlier, latency hidden. Next-tile stages issue at phases 0/1 and
// stay in flight across the per-phase raw s_barriers (never drained early).
__global__ __launch_bounds__(512, 1) void gemm_qkv(const u16* __restrict__ A,
                                                   const u16* __restrict__ W,
                                                   u16* __restrict__ qo,
                                                   u16* __restrict__ ko,
                                                   u16* __restrict__ vo) {
    const int id = blockIdx.x;               // 768 blocks
    const int xcd = id & 7, rr_ = id >> 3;   // XCD-chunked: each XCD owns 8 A-panels
    const int bm = xcd * 8 + (rr_ & 7);      // 0..63
    const int bn = rr_ >> 3;                 // 0..11
    const int tid = threadIdx.x;
    const int w = tid >> 6, lane = tid & 63, quad = lane >> 4, l16 = lane & 15;
    const int wm = w >> 2, wn = w & 3;       // 2M x 4N waves, wave tile 128x64

    __shared__ u16 smem[2 * 32768];          // 128 KB: 2 buf x (A 256x64 | B 256x64)

    f32x4 acc[8][4] = {};                    // 8 m-frags x 4 n-frags of 16x16

    const u16* Ab = A + (size_t)(bm * 256) * E_;
    const u16* Wb = W + (size_t)(bn * 256) * E_;

    // stage one half-tile (128 rows x 64 cols): linear LDS dest, source chunk
    // pre-swizzled c = s8 ^ (row&7). 1024 chunks over 512 threads = 2 gload each.
    auto stage_half = [&](int buf, int mat, int rh, int kt, const u16* gb) {
#pragma unroll
        for (int s = 0; s < 2; s++) {
            int q = s * 512 + tid;
            int row = rh * 128 + (q >> 3), s8 = q & 7;
            int c = s8 ^ (row & 7);
            gload_lds16(gb + (size_t)row * E_ + kt * 64 + c * 8,
                        &smem[buf * 32768 + mat * 16384 + (row * 8 + s8) * 8]);
        }
    };

    // prologue: K-tile 0 into buf 0 (8 gload_lds in flight)
    stage_half(0, 0, 0, 0, Ab); stage_half(0, 0, 1, 0, Ab);
    stage_half(0, 1, 0, 0, Wb); stage_half(0, 1, 1, 0, Wb);

    for (int k = 0; k < 16; k++) {
        const int cur = k & 1;
        u16* As = &smem[cur * 32768];
        u16* Bs = &smem[cur * 32768 + 16384];

        // ---- tile start: full drain. My stages for buf cur landed (vmcnt(0)),
        // barrier => everyone's did. __syncthreads emits exactly vmcnt(0)+
        // lgkmcnt(0)+s_barrier — the intended semantics at this one point.
        __syncthreads();

#pragma unroll
        for (int p = 0; p < 4; p++) {
            const int mh = p >> 1, ks = p & 1;
            // 8 x ds_read_b128: 4 A-frags (m-half mh, ks) + 4 B-frags (ks)
            bf16x8 af[4], bfr[4];
#pragma unroll
            for (int ii = 0; ii < 4; ii++) {
                int R = wm * 128 + (mh * 4 + ii) * 16 + l16;
                int c = ks * 4 + quad;
                af[ii] = load_frag(&As[(R * 8 + (c ^ (R & 7))) * 8]);
            }
#pragma unroll
            for (int jj = 0; jj < 4; jj++) {
                int R = wn * 64 + jj * 16 + l16;
                int c = ks * 4 + quad;
                bfr[jj] = load_frag(&Bs[(R * 8 + (c ^ (R & 7))) * 8]);
            }
            // issue next K-tile's stages early: p0 = A halves, p1 = B halves.
            // buf cur^1 is free: all reads of it finished before this tile's
            // start barrier (each wave's lgkmcnt(0) preceded its last MFMA).
            if (k < 15 && p < 2) {
                stage_half(cur ^ 1, p, 0, k + 1, p ? Wb : Ab);
                stage_half(cur ^ 1, p, 1, k + 1, p ? Wb : Ab);
            }
            __builtin_amdgcn_sched_barrier(0);
            __builtin_amdgcn_s_barrier();
            asm volatile("s_waitcnt lgkmcnt(0)" ::: "memory");
            __builtin_amdgcn_sched_barrier(0);
            __builtin_amdgcn_s_setprio(1);
#pragma unroll
            for (int ii = 0; ii < 4; ii++)
#pragma unroll
                for (int jj = 0; jj < 4; jj++)
                    acc[mh * 4 + ii][jj] = __builtin_amdgcn_mfma_f32_16x16x32_bf16(
                        af[ii], bfr[jj], acc[mh * 4 + ii][jj], 0, 0, 0);
            __builtin_amdgcn_s_setprio(0);
            __builtin_amdgcn_s_barrier();
        }
    }

    // ---- epilogue: acc -> LDS bf16 (256x256 staged, swizzled) -> coalesced stores ----
    // C/D frag: col = lane&15, row = quad*4 + reg. Safe to overwrite smem: every
    // wave consumed its ds_reads (lgkmcnt(0)) before its last MFMA, and the final
    // phase s_barrier gates all waves past that point.
    if (bn < 8) {
        // [m][n]: elem(m,n) @ m*256 + ((n>>3 ^ (m&31))<<3) + (n&7)
#pragma unroll
        for (int i = 0; i < 8; i++)
#pragma unroll
            for (int j = 0; j < 4; j++) {
                int n = wn * 64 + j * 16 + l16;
#pragma unroll
                for (int rg = 0; rg < 4; rg++) {
                    int m = wm * 128 + i * 16 + quad * 4 + rg;
                    smem[m * 256 + (((n >> 3) ^ (m & 31)) << 3) + (n & 7)] =
                        f2bf(acc[i][j][rg]);
                }
            }
    } else {
        // [n][m], pack 4 consecutive m
#pragma unroll
        for (int i = 0; i < 8; i++)
#pragma unroll
            for (int j = 0; j < 4; j++) {
                int n = wn * 64 + j * 16 + l16;
                int m0 = wm * 128 + i * 16 + quad * 4;
                u16x4 pk;
#pragma unroll
                for (int rg = 0; rg < 4; rg++) pk[rg] = f2bf(acc[i][j][rg]);
                *(u16x4*)&smem[n * 256 + (((m0 >> 3) ^ (n & 31)) << 3) + (m0 & 7)] = pk;
            }
    }
    __syncthreads();

    const int b = bm >> 3;
    if (bn < 4) {
        // Q row-major
#pragma unroll
        for (int i = 0; i < 16; i++) {
            int c = i * 512 + tid;
            int m = c >> 5, nc = c & 31;
            u16x8 v = *(u16x8*)&smem[m * 256 + ((nc ^ (m & 31)) << 3)];
            *(u16x8*)&qo[(size_t)(bm * 256 + m) * H_ + bn * 256 + nc * 8] = v;
        }
    } else if (bn < 8) {
        // K frag-native
#pragma unroll
        for (int i = 0; i < 16; i++) {
            int c = i * 512 + tid;
            int ln = c & 63, h16c = (c >> 6) & 15, s32c = c >> 10;
            int m = s32c * 32 + (ln & 31);
            int nc = h16c * 2 + (ln >> 5);
            u16x8 v = *(u16x8*)&smem[m * 256 + ((nc ^ (m & 31)) << 3)];
            int s32g = (bm & 7) * 8 + s32c;
            int h16g = (bn - 4) * 16 + h16c;
            *(u16x8*)&ko[(((size_t)b * 64 + s32g) * 64 + h16g) * 512 + ln * 8] = v;
        }
    } else {
        // V frag-native
#pragma unroll
        for (int i = 0; i < 16; i++) {
            int c = i * 512 + tid;
            int ln = c & 63, s16c = (c >> 6) & 15, h32c = c >> 10;
            int n = h32c * 32 + (ln & 31);
            int mc = s16c * 2 + (ln >> 5);
            u16x8 v = *(u16x8*)&smem[n * 256 + ((mc ^ (n & 31)) << 3)];
            int h32g = (bn - 8) * 8 + h32c;
            int s16g = (bm & 7) * 16 + s16c;
            *(u16x8*)&vo[(((size_t)b * 32 + h32g) * 128 + s16g) * 512 + ln * 8] = v;
        }
    }
}

// ---------------- flash attention (round-1 verified): XCD-pinned batches + V reg-prefetch ----
// 64 q-rows/block, 8 waves. LDS = Qs 128K + 2x16K bf16 S-partials = 160 KiB.
// Grid: 1-D 256 blocks. batch = bid & 7 pins each batch's blocks to one XCD;
// all 32 blocks of a batch stream s0 in loose lockstep -> shared L2 window.
__global__ __launch_bounds__(512, 2) void attn(const u16* __restrict__ qb,
                                               const u16* __restrict__ kfg,
                                               const u16* __restrict__ vfg,
                                               float* __restrict__ out) {
    const int bid = blockIdx.x;
    const int b = bid & 7;           // batch == XCD
    const int qt = bid >> 3;         // 0..31
    const int t0 = (31 - qt) * 64;
    const int tid = threadIdx.x;
    const int w = tid >> 6, lane = tid & 63;
    const int l5 = lane >> 5, l31 = lane & 31;
    const int srow = tid >> 3, sg = tid & 7;

    __shared__ u16 Qs[64 * 1024];   // 128 KB, [row][chunk ^ (row&7)]
    __shared__ u16 Sp[2 * 64 * 128]; // 32 KB: two bf16 [64][128] partials (chunk-swizzled)
    float* alphas = (float*)(Sp + 8192);  // aliases Sp1[0..255B]; written after Sp1 reads

    const u16* qB = qb + (size_t)b * T_ * H_;
    const u16* kfB = kfg + (size_t)b * 2097152;
    const u16* vfB = vfg + (size_t)b * 2097152;
    const float scale = 0.03125f;   // E^-0.5

    // stage Q
#pragma unroll
    for (int i = 0; i < 16; i++) {
        int s = i * 512 + tid;
        int row = s >> 7, c = s & 127;
        int cc = c ^ (row & 7);
        gload_lds16(qB + (size_t)(t0 + row) * H_ + cc * 8, &Qs[s * 8]);
    }

    float m_r = -INF, l_r = 0.f;
    f32x16 o[2][4] = {};   // [rowgroup][h-tile]; wave w: H cols [w*128, w*128+128)

    const int ct = w & 3;        // S col-tile (32 cols)
    const int kh = w >> 2;       // k-half

    __syncthreads();   // Q staged

    for (int s0 = 0; s0 <= t0 + 63; s0 += 128) {
        // ---- V prefetch group 0 (addresses depend only on s0): issued before
        // phase 1 so the latency is hidden under the whole QK^T phase.
        const u16* vp = vfB + ((size_t)(w * 4) * 128 + (s0 >> 4)) * 512 + lane * 8;
        bf16x8 vbuf[3][4];
#pragma unroll
        for (int ht = 0; ht < 4; ht++)
            vbuf[0][ht] = load_frag(vp + (size_t)ht * 128 * 512);

        // ---- phase 1: partial scores, wave: cols ct*32..+32, k in [kh*512, kh*512+512)
        f32x16 sa0 = {}, sa1 = {};
        {
            const u16* kp = kfB + (((size_t)((s0 >> 5) + ct)) * 64 + kh * 32) * 512 + lane * 8;
#pragma unroll 8
            for (int st = 0; st < 32; st++) {
                bf16x8 kf = load_frag(kp + st * 512);
                int cb = (kh * 32 + st) * 2 + l5;
                int x0 = l31 & 7;   // (32+l31)&7 == l31&7
                bf16x8 a0 = load_frag(&Qs[((size_t)l31 * 128 + (cb ^ x0)) * 8]);
                bf16x8 a1 = load_frag(&Qs[((size_t)(32 + l31) * 128 + (cb ^ x0)) * 8]);
                __builtin_amdgcn_s_setprio(1);
                sa0 = __builtin_amdgcn_mfma_f32_32x32x16_bf16(a0, kf, sa0, 0, 0, 0);
                sa1 = __builtin_amdgcn_mfma_f32_32x32x16_bf16(a1, kf, sa1, 0, 0, 0);
                __builtin_amdgcn_s_setprio(0);
            }
        }
        __syncthreads();   // prev PV done reading P(Sp0) + alphas(Sp1)
        {
            u16* Sdst = Sp + kh * 8192;
            int col = ct * 32 + l31;
            int chc = col >> 3, cil = col & 7;
#pragma unroll
            for (int reg = 0; reg < 16; reg++) {
                int row = (reg & 3) + 8 * (reg >> 2) + 4 * l5;
                Sdst[(row * 16 + (chc ^ (row & 7))) * 8 + cil] = f2bf(sa0[reg] * scale);
                int row1 = row + 32;
                Sdst[(row1 * 16 + (chc ^ (row1 & 7))) * 8 + cil] = f2bf(sa1[reg] * scale);
            }
        }
        __syncthreads();   // partials visible

        // ---- phase 2: softmax. thread (srow, sg): cols sg*16..+16
        {
            int sw0 = (sg * 2) ^ (srow & 7), sw1 = (sg * 2 + 1) ^ (srow & 7);
            u16x8 a0 = *(u16x8*)&Sp[(srow * 16 + sw0) * 8];
            u16x8 a1 = *(u16x8*)&Sp[(srow * 16 + sw1) * 8];
            u16x8 b0 = *(u16x8*)&Sp[8192 + (srow * 16 + sw0) * 8];
            u16x8 b1 = *(u16x8*)&Sp[8192 + (srow * 16 + sw1) * 8];
            float v[16];
#pragma unroll
            for (int j = 0; j < 8; j++) v[j] = bf2f(a0[j]) + bf2f(b0[j]);
#pragma unroll
            for (int j = 0; j < 8; j++) v[8 + j] = bf2f(a1[j]) + bf2f(b1[j]);
            int colb = sg * 16;
#pragma unroll
            for (int j = 0; j < 16; j++)
                if (s0 + colb + j > t0 + srow) v[j] = -INF;
            float rmax = v[0];
#pragma unroll
            for (int j = 1; j < 16; j++) rmax = fmaxf(rmax, v[j]);
#pragma unroll
            for (int off = 4; off >= 1; off >>= 1) rmax = fmaxf(rmax, __shfl_xor(rmax, off, 64));
            float mn = fmaxf(m_r, rmax);
            float alpha = __expf(m_r - mn);
            float rsum = 0.f;
            u16x8 p0, p1;
#pragma unroll
            for (int j = 0; j < 8; j++) {
                float p = __expf(v[j] - mn);
                rsum += p; p0[j] = f2bf(p);
            }
#pragma unroll
            for (int j = 0; j < 8; j++) {
                float p = __expf(v[8 + j] - mn);
                rsum += p; p1[j] = f2bf(p);
            }
#pragma unroll
            for (int off = 4; off >= 1; off >>= 1) rsum += __shfl_xor(rsum, off, 64);
            l_r = l_r * alpha + rsum;
            m_r = mn;
            // P in-place over the exact slots this thread read from Sp0
            *(u16x8*)&Sp[(srow * 16 + sw0) * 8] = p0;
            *(u16x8*)&Sp[(srow * 16 + sw1) * 8] = p1;
            __syncthreads();   // all Sp1 reads done
            if (sg == 0) alphas[srow] = alpha;
        }
        __syncthreads();   // P + alphas visible

        // ---- phase 3: PV. wave w: h cols w*128..+128, all 64 rows
        // V triple-buffered, 2 groups ahead; group 0 arrived during phase 1.
        {
#pragma unroll
            for (int rg = 0; rg < 2; rg++)
#pragma unroll
                for (int reg = 0; reg < 16; reg++) {
                    float al = alphas[rg * 32 + (reg & 3) + 8 * (reg >> 2) + 4 * l5];
#pragma unroll
                    for (int ht = 0; ht < 4; ht++) o[rg][ht][reg] *= al;
                }
            int xp = l31 & 7;
#pragma unroll
            for (int ht = 0; ht < 4; ht++)
                vbuf[1][ht] = load_frag(vp + ((size_t)ht * 128 + 1) * 512);
#pragma unroll
            for (int sc = 0; sc < 8; sc++) {
                if (sc < 6) {
#pragma unroll
                    for (int ht = 0; ht < 4; ht++)
                        vbuf[(sc + 2) % 3][ht] = load_frag(vp + ((size_t)ht * 128 + sc + 2) * 512);
                }
                bf16x8 p0 = load_frag(&Sp[((size_t)l31 * 16 + ((sc * 2 + l5) ^ xp)) * 8]);
                bf16x8 p1 = load_frag(&Sp[((size_t)(32 + l31) * 16 + ((sc * 2 + l5) ^ xp)) * 8]);
                __builtin_amdgcn_s_setprio(1);
#pragma unroll
                for (int ht = 0; ht < 4; ht++) {
                    o[0][ht] = __builtin_amdgcn_mfma_f32_32x32x16_bf16(p0, vbuf[sc % 3][ht], o[0][ht], 0, 0, 0);
                    o[1][ht] = __builtin_amdgcn_mfma_f32_32x32x16_bf16(p1, vbuf[sc % 3][ht], o[1][ht], 0, 0, 0);
                }
                __builtin_amdgcn_s_setprio(0);
            }
        }
    }

    // ---- epilogue
    __syncthreads();
    if (sg == 0) alphas[srow] = l_r;
    __syncthreads();
    float* ob = out + (size_t)b * T_ * H_;
#pragma unroll
    for (int rg = 0; rg < 2; rg++)
#pragma unroll
        for (int reg = 0; reg < 16; reg++) {
            int row = rg * 32 + (reg & 3) + 8 * (reg >> 2) + 4 * l5;
            float linv = 1.f / alphas[row];
#pragma unroll
            for (int ht = 0; ht < 4; ht++) {
                int col = w * 128 + ht * 32 + l31;
                ob[(size_t)(t0 + row) * H_ + col] = o[rg][ht][reg] * linv;
            }
        }
}

extern "C" void kernel_launch(void* const* d_in, const int* in_sizes, int n_in,
                              void* d_out, int out_size, void* d_ws, size_t ws_size,
                              hipStream_t stream) {
    const float* x  = (const float*)d_in[0];
    const float* Wk = (const float*)d_in[1];
    const float* Wq = (const float*)d_in[2];
    const float* Wv = (const float*)d_in[3];
    float* out = (float*)d_out;

    char* ws = (char*)d_ws;
    const size_t SZ_XB  = (size_t)M_ * E_ * 2;
    const size_t SZ_W   = (size_t)3 * H_ * E_ * 2;
    const size_t SZ_QKV = (size_t)M_ * H_ * 2;
    u16* xb   = (u16*)(ws);
    u16* wqkv = (u16*)(ws + SZ_XB);
    u16* qb   = (u16*)(ws + SZ_XB + SZ_W);
    u16* kfb  = (u16*)(ws + SZ_XB + SZ_W + SZ_QKV);
    u16* vfb  = (u16*)(ws + SZ_XB + SZ_W + 2 * SZ_QKV);

    castk<<<M_ * E_ / 4 / 256, 256, 0, stream>>>(x, xb, M_ * E_);
    castk<<<H_ * E_ / 4 / 256, 256, 0, stream>>>(Wq, wqkv, H_ * E_);
    castk<<<H_ * E_ / 4 / 256, 256, 0, stream>>>(Wk, wqkv + (size_t)H_ * E_, H_ * E_);
    castk<<<H_ * E_ / 4 / 256, 256, 0, stream>>>(Wv, wqkv + (size_t)2 * H_ * E_, H_ * E_);

    gemm_qkv<<<dim3(768), 512, 0, stream>>>(xb, wqkv, qb, kfb, vfb);

    attn<<<dim3(256), 512, 0, stream>>>(qb, kfb, vfb, out);
}